// Round 1
// baseline (468.532 us; speedup 1.0000x reference)
//
#include <hip/hip_runtime.h>
#include <hip/hip_fp16.h>
#include <math.h>

typedef _Float16 half_t;
typedef _Float16 half8 __attribute__((ext_vector_type(8)));
typedef float f32x4 __attribute__((ext_vector_type(4)));

#define MFMA(a, b, c) __builtin_amdgcn_mfma_f32_16x16x32_f16((a), (b), (c), 0, 0, 0)

static constexpr float kScale = 0.2041241452319315f;  // 24^-0.5
static constexpr int QSTR = 200;  // qbuf (Q|K -> O -> h1 staging) row stride, halves
static constexpr int VTS  = 72;   // vT / pbuf row stride
static constexpr int XNS  = 104;  // xn row stride

// ---- weights -> fp16, plus rel-pos bias expanded to [head][i][j] fp32 (64 KB)
__global__ __launch_bounds__(256) void k_convert(const float* __restrict__ qkv_w,
                                                 const float* __restrict__ proj_w,
                                                 const float* __restrict__ fc1_w,
                                                 const float* __restrict__ fc2_w,
                                                 const float* __restrict__ tbl,
                                                 half_t* __restrict__ wbuf,
                                                 float* __restrict__ biasT) {
  int i = blockIdx.x * 256 + threadIdx.x;  // grid 496*256 = 126976 >= 110592+16384
  if (i < 27648)        wbuf[i] = (half_t)qkv_w[i];
  else if (i < 36864)   wbuf[i] = (half_t)proj_w[i - 27648];
  else if (i < 73728)   wbuf[i] = (half_t)fc1_w[i - 36864];
  else if (i < 110592)  wbuf[i] = (half_t)fc2_w[i - 73728];
  else if (biasT != nullptr) {
    int j = i - 110592;                  // [head][i][j] : 4 * 64 * 64
    int h = j >> 12, rem = j & 4095;
    int ii = rem >> 6, jj = rem & 63;
    int ih = ii >> 3, iw = ii & 7, jh = jj >> 3, jw = jj & 7;
    biasT[j] = tbl[((ih - jh + 7) * 15 + (iw - jw + 7)) * 4 + h];
  }
}

// ===== whole Swin block fused; wave g owns token rows g*16..g*16+15 throughout.
// LDS 40640 B -> 4 blocks/CU. Two barriers total.
//   qbuf @0     : 25600 B  Q|K (stride 200) -> O (same rows) -> h1 staging (wave-private rows)
//   vbuf @25600 : 15040 B  vT (stride 72, padded for head3 over-read) -> per-head pbuf -> xn
__global__ __launch_bounds__(256, 4) void k_swin(
    const float* __restrict__ x,
    const float* __restrict__ n1g, const float* __restrict__ n1b,
    const half_t* __restrict__ qkvw, const float* __restrict__ qkv_b,
    const float* __restrict__ tbl_g, const float* __restrict__ biasT,
    const half_t* __restrict__ projw, const float* __restrict__ proj_b,
    const float* __restrict__ n2g, const float* __restrict__ n2b,
    const half_t* __restrict__ fc1w, const float* __restrict__ fc1b,
    const half_t* __restrict__ fc2w, const float* __restrict__ fc2b,
    float* __restrict__ out) {
  __shared__ __attribute__((aligned(16))) unsigned char smem[40640];
  half_t* qbuf = (half_t*)smem;
  half_t* vbuf = (half_t*)(smem + 25600);

  int tid = threadIdx.x;
  int wave = tid >> 6, lane = tid & 63;
  int l15 = lane & 15, quad = lane >> 4;
  int blk = blockIdx.x;                        // bb*64 + wh*8 + ww
  int bb = blk >> 6, wh = (blk >> 3) & 7, ww = blk & 7;

  // ---- A: LN1 in registers; output IS the MFMA A-fragment (row=l15, col=quad*8+..)
  half8 af[3];
  {
    int tok = wave * 16 + l15;
    int sr = (wh * 8 + (tok >> 3) + 4) & 63;
    int sc = (ww * 8 + (tok & 7) + 4) & 63;
    const float* rp = x + ((size_t)bb * 4096 + sr * 64 + sc) * 96;
    float v[24];
    float s1 = 0.f, s2 = 0.f;
#pragma unroll
    for (int kt = 0; kt < 3; ++kt) {
      float4 a = *(const float4*)(rp + kt * 32 + quad * 8);
      float4 b = *(const float4*)(rp + kt * 32 + quad * 8 + 4);
      v[kt*8+0]=a.x; v[kt*8+1]=a.y; v[kt*8+2]=a.z; v[kt*8+3]=a.w;
      v[kt*8+4]=b.x; v[kt*8+5]=b.y; v[kt*8+6]=b.z; v[kt*8+7]=b.w;
    }
#pragma unroll
    for (int c = 0; c < 24; ++c) { s1 += v[c]; s2 += v[c] * v[c]; }
    s1 += __shfl_xor(s1, 16); s1 += __shfl_xor(s1, 32);
    s2 += __shfl_xor(s2, 16); s2 += __shfl_xor(s2, 32);
    float mu = s1 * (1.f / 96.f);
    float inv = rsqrtf(fmaxf(s2 * (1.f / 96.f) - mu * mu, 0.f) + 1e-5f);
#pragma unroll
    for (int kt = 0; kt < 3; ++kt) {
      int c0 = kt * 32 + quad * 8;
      float4 g0 = *(const float4*)(n1g + c0);
      float4 g1 = *(const float4*)(n1g + c0 + 4);
      float4 b0 = *(const float4*)(n1b + c0);
      float4 b1 = *(const float4*)(n1b + c0 + 4);
      float gg[8] = {g0.x,g0.y,g0.z,g0.w,g1.x,g1.y,g1.z,g1.w};
      float bv[8] = {b0.x,b0.y,b0.z,b0.w,b1.x,b1.y,b1.z,b1.w};
      half8 hh;
#pragma unroll
      for (int j = 0; j < 8; ++j)
        hh[j] = (half_t)((v[kt*8+j] - mu) * inv * gg[j] + bv[j]);
      af[kt] = hh;
    }
  }

  // ---- B: QKV GEMM, wave g computes its 16 rows for all 18 col tiles (balanced)
  {
#pragma unroll
    for (int t = 0; t < 18; ++t) {
      int n0 = t * 16 + l15;
      const half_t* wp = qkvw + (size_t)n0 * 96 + quad * 8;
      half8 b0 = *(const half8*)(wp);
      half8 b1 = *(const half8*)(wp + 32);
      half8 b2 = *(const half8*)(wp + 64);
      f32x4 acc = {0, 0, 0, 0};
      acc = MFMA(af[0], b0, acc);
      acc = MFMA(af[1], b1, acc);
      acc = MFMA(af[2], b2, acc);
      float bias = qkv_b[n0];
      if (t < 12) {                      // Q (scaled) and K -> qbuf cols n0
        float sc_ = (t < 6) ? kScale : 1.f;
#pragma unroll
        for (int r = 0; r < 4; ++r)
          qbuf[(wave * 16 + quad * 4 + r) * QSTR + n0] = (half_t)((acc[r] + bias) * sc_);
      } else {                           // V -> vT [head][c][token]
        int vc = n0 - 192;
        int hd = vc / 24, c = vc - hd * 24;
#pragma unroll
        for (int r = 0; r < 4; ++r)
          vbuf[hd * 24 * VTS + c * VTS + wave * 16 + quad * 4 + r] = (half_t)(acc[r] + bias);
      }
    }
  }
  __syncthreads();  // B1: Q,K,V staged

  // ---- C: attention, wave = head. Softmax folded per 16-row group; P*inv -> pbuf
  {
    int head = wave;
    const half8 z8 = {};
    half8 kb[4], vb[2][2];
#pragma unroll
    for (int nt = 0; nt < 4; ++nt) {
      half8 t = *(const half8*)(&qbuf[(nt * 16 + l15) * QSTR + 96 + head * 24 + quad * 8]);
      kb[nt] = (quad < 3) ? t : z8;
    }
#pragma unroll
    for (int nt = 0; nt < 2; ++nt)
#pragma unroll
      for (int kt = 0; kt < 2; ++kt)
        vb[nt][kt] = *(const half8*)(&vbuf[head * 24 * VTS + (nt * 16 + l15) * VTS + kt * 32 + quad * 8]);

    int rj[4], jh_[4], jw_[4];
#pragma unroll
    for (int nt = 0; nt < 4; ++nt) {
      int j = nt * 16 + l15;
      jh_[nt] = j >> 3; jw_[nt] = j & 7;
      int rr = wh * 8 + jh_[nt], cc = ww * 8 + jw_[nt];
      rj[nt] = ((rr < 56) ? 0 : ((rr < 60) ? 1 : 2)) * 3 + ((cc < 56) ? 0 : ((cc < 60) ? 1 : 2));
    }

    half_t* pb = vbuf + head * 24 * VTS;   // wave-private alias over own vT slice
    f32x4 oacc[4][2];

#pragma unroll
    for (int g2 = 0; g2 < 4; ++g2) {
      half8 qt = *(const half8*)(&qbuf[(g2 * 16 + l15) * QSTR + head * 24 + quad * 8]);
      half8 qa = (quad < 3) ? qt : z8;
      f32x4 sv[4];
#pragma unroll
      for (int nt = 0; nt < 4; ++nt) {
        f32x4 a = {0, 0, 0, 0};
        sv[nt] = MFMA(qa, kb[nt], a);
      }
      float pinv[4];
#pragma unroll
      for (int r = 0; r < 4; ++r) {
        int i = g2 * 16 + quad * 4 + r;
        int ih = i >> 3, iw = i & 7;
        int rr = wh * 8 + ih, cc = ww * 8 + iw;
        int ri = ((rr < 56) ? 0 : ((rr < 60) ? 1 : 2)) * 3 + ((cc < 56) ? 0 : ((cc < 60) ? 1 : 2));
        float bvv[4];
        if (biasT != nullptr) {
          const float* bp = biasT + (head << 12) + (i << 6) + l15;
#pragma unroll
          for (int nt = 0; nt < 4; ++nt) bvv[nt] = bp[nt * 16];
        } else {
#pragma unroll
          for (int nt = 0; nt < 4; ++nt)
            bvv[nt] = tbl_g[((ih - jh_[nt] + 7) * 15 + (iw - jw_[nt] + 7)) * 4 + head];
        }
#pragma unroll
        for (int nt = 0; nt < 4; ++nt) {
          float val = sv[nt][r] + bvv[nt];
          if (ri != rj[nt]) val -= 100.f;
          sv[nt][r] = val;
        }
        float mx = fmaxf(fmaxf(sv[0][r], sv[1][r]), fmaxf(sv[2][r], sv[3][r]));
        mx = fmaxf(mx, __shfl_xor(mx, 1));
        mx = fmaxf(mx, __shfl_xor(mx, 2));
        mx = fmaxf(mx, __shfl_xor(mx, 4));
        mx = fmaxf(mx, __shfl_xor(mx, 8));
        float sum = 0.f;
#pragma unroll
        for (int nt = 0; nt < 4; ++nt) {
          float e = __expf(sv[nt][r] - mx);
          sv[nt][r] = e;
          sum += e;
        }
        sum += __shfl_xor(sum, 1);
        sum += __shfl_xor(sum, 2);
        sum += __shfl_xor(sum, 4);
        sum += __shfl_xor(sum, 8);
        pinv[r] = __builtin_amdgcn_rcpf(sum);
      }
      // normalized P (C layout) -> pb, read back as A-frags (same wave, in-order DS)
#pragma unroll
      for (int nt = 0; nt < 4; ++nt)
#pragma unroll
        for (int r = 0; r < 4; ++r)
          pb[(quad * 4 + r) * VTS + nt * 16 + l15] = (half_t)(sv[nt][r] * pinv[r]);
      __builtin_amdgcn_sched_barrier(0);
      half8 pa0 = *(const half8*)(&pb[l15 * VTS + quad * 8]);
      half8 pa1 = *(const half8*)(&pb[l15 * VTS + 32 + quad * 8]);
#pragma unroll
      for (int nt = 0; nt < 2; ++nt) {
        f32x4 a = {0, 0, 0, 0};
        a = MFMA(pa0, vb[nt][0], a);
        a = MFMA(pa1, vb[nt][1], a);
        oacc[g2][nt] = a;
      }
    }
    // O -> qbuf cols head*24..+23 (only masked quad-3 lanes of neighbors read these)
#pragma unroll
    for (int g2 = 0; g2 < 4; ++g2)
#pragma unroll
      for (int nt = 0; nt < 2; ++nt) {
        int c = nt * 16 + l15;
        if (c < 24)
#pragma unroll
          for (int r = 0; r < 4; ++r)
            qbuf[(g2 * 16 + quad * 4 + r) * QSTR + head * 24 + c] = (half_t)oacc[g2][nt][r];
      }
  }
  __syncthreads();  // B3: all heads' O columns visible; afterwards all rows wave-private

  // ---- D: proj + residual + LN2 fused (wave-private rows; residual stays in regs)
  float rv[6][4];
  int foff[4];
  half8 a5[3];
  {
    half8 oa[3];
#pragma unroll
    for (int kt = 0; kt < 3; ++kt)
      oa[kt] = *(const half8*)(&qbuf[(wave * 16 + l15) * QSTR + kt * 32 + quad * 8]);
    f32x4 acc[6];
#pragma unroll
    for (int t = 0; t < 6; ++t) {
      int n0 = t * 16 + l15;
      const half_t* wp = projw + (size_t)n0 * 96 + quad * 8;
      half8 b0 = *(const half8*)(wp);
      half8 b1 = *(const half8*)(wp + 32);
      half8 b2 = *(const half8*)(wp + 64);
      f32x4 a = {0, 0, 0, 0};
      a = MFMA(oa[0], b0, a);
      a = MFMA(oa[1], b1, a);
      a = MFMA(oa[2], b2, a);
      acc[t] = a;
    }
    float xv[6][4];
#pragma unroll
    for (int r = 0; r < 4; ++r) {
      int tok = wave * 16 + quad * 4 + r;
      int sr = (wh * 8 + (tok >> 3) + 4) & 63;
      int sc = (ww * 8 + (tok & 7) + 4) & 63;
      foff[r] = (bb * 4096 + sr * 64 + sc) * 96 + l15;
      const float* xp = x + foff[r];
#pragma unroll
      for (int t = 0; t < 6; ++t) xv[t][r] = xp[t * 16];
    }
    float s1[4] = {0, 0, 0, 0}, s2[4] = {0, 0, 0, 0};
#pragma unroll
    for (int t = 0; t < 6; ++t) {
      float pbv = proj_b[t * 16 + l15];
#pragma unroll
      for (int r = 0; r < 4; ++r) {
        float vvv = xv[t][r] + acc[t][r] + pbv;
        rv[t][r] = vvv;
        s1[r] += vvv; s2[r] += vvv * vvv;
      }
    }
    float mu[4], nv[4];
#pragma unroll
    for (int r = 0; r < 4; ++r) {
      s1[r] += __shfl_xor(s1[r], 1); s1[r] += __shfl_xor(s1[r], 2);
      s1[r] += __shfl_xor(s1[r], 4); s1[r] += __shfl_xor(s1[r], 8);
      s2[r] += __shfl_xor(s2[r], 1); s2[r] += __shfl_xor(s2[r], 2);
      s2[r] += __shfl_xor(s2[r], 4); s2[r] += __shfl_xor(s2[r], 8);
      mu[r] = s1[r] * (1.f / 96.f);
      nv[r] = rsqrtf(fmaxf(s2[r] * (1.f / 96.f) - mu[r] * mu[r], 0.f) + 1e-5f);
    }
    half_t* xnb = vbuf;  // vT/pbuf dead after B3; wave-private rows
#pragma unroll
    for (int t = 0; t < 6; ++t) {
      int n0 = t * 16 + l15;
      float gv = n2g[n0], bv = n2b[n0];
#pragma unroll
      for (int r = 0; r < 4; ++r)
        xnb[(wave * 16 + quad * 4 + r) * XNS + n0] =
            (half_t)((rv[t][r] - mu[r]) * nv[r] * gv + bv);
    }
    __builtin_amdgcn_sched_barrier(0);
#pragma unroll
    for (int kt = 0; kt < 3; ++kt)
      a5[kt] = *(const half8*)(&xnb[(wave * 16 + l15) * XNS + kt * 32 + quad * 8]);
  }

  // ---- E: MLP, K-split (kb), zero barriers; h1 staged in own qbuf rows
  f32x4 acc6[6];
#pragma unroll
  for (int t = 0; t < 6; ++t) acc6[t] = (f32x4){0, 0, 0, 0};
#pragma unroll 1
  for (int kb = 0; kb < 2; ++kb) {
#pragma unroll
    for (int th = 0; th < 12; ++th) {
      int n0 = (kb * 12 + th) * 16 + l15;
      const half_t* wp = fc1w + (size_t)n0 * 96 + quad * 8;
      half8 b0 = *(const half8*)(wp);
      half8 b1 = *(const half8*)(wp + 32);
      half8 b2 = *(const half8*)(wp + 64);
      f32x4 a = {0, 0, 0, 0};
      a = MFMA(a5[0], b0, a);
      a = MFMA(a5[1], b1, a);
      a = MFMA(a5[2], b2, a);
      float fb = fc1b[n0];
#pragma unroll
      for (int r = 0; r < 4; ++r) {
        float vvv = a[r] + fb;
        // GELU (tanh/sigmoid form): v * sigmoid(v*(1.5957691 + 0.14270963*v^2))
        float u = vvv * (1.5957691216f + 0.1427096322f * vvv * vvv);
        float g = vvv * __builtin_amdgcn_rcpf(1.f + __expf(-u));
        qbuf[(wave * 16 + quad * 4 + r) * QSTR + th * 16 + l15] = (half_t)g;
      }
    }
    __builtin_amdgcn_sched_barrier(0);
#pragma unroll
    for (int kk = 0; kk < 6; ++kk) {
      half8 ha = *(const half8*)(&qbuf[(wave * 16 + l15) * QSTR + kk * 32 + quad * 8]);
#pragma unroll
      for (int t6 = 0; t6 < 6; ++t6) {
        half8 bf = *(const half8*)(fc2w + (size_t)(t6 * 16 + l15) * 384 + kb * 192 + kk * 32 + quad * 8);
        acc6[t6] = MFMA(ha, bf, acc6[t6]);
      }
    }
    __builtin_amdgcn_sched_barrier(0);
  }

  // ---- F: out = residual + fc2 + bias (residual from registers)
#pragma unroll
  for (int t6 = 0; t6 < 6; ++t6) {
    float fb = fc2b[t6 * 16 + l15];
#pragma unroll
    for (int r = 0; r < 4; ++r)
      out[(size_t)foff[r] + t6 * 16] = rv[t6][r] + acc6[t6][r] + fb;
  }
}

extern "C" void kernel_launch(void* const* d_in, const int* in_sizes, int n_in,
                              void* d_out, int out_size, void* d_ws, size_t ws_size,
                              hipStream_t stream) {
  const float* x      = (const float*)d_in[0];
  const float* n1g    = (const float*)d_in[1];
  const float* n1b    = (const float*)d_in[2];
  const float* qkv_w  = (const float*)d_in[3];
  const float* qkv_b  = (const float*)d_in[4];
  const float* rtbl   = (const float*)d_in[5];
  const float* proj_w = (const float*)d_in[6];
  const float* proj_b = (const float*)d_in[7];
  const float* n2g    = (const float*)d_in[8];
  const float* n2b    = (const float*)d_in[9];
  const float* fc1_w  = (const float*)d_in[10];
  const float* fc1_b  = (const float*)d_in[11];
  const float* fc2_w  = (const float*)d_in[12];
  const float* fc2_b  = (const float*)d_in[13];
  float* out = (float*)d_out;

  if (ws_size < 221184) return;
  half_t* wbuf = (half_t*)d_ws;
  float* biasT = (ws_size >= 221184 + 65536) ? (float*)((char*)d_ws + 221184) : nullptr;

  k_convert<<<496, 256, 0, stream>>>(qkv_w, proj_w, fc1_w, fc2_w, rtbl, wbuf, biasT);
  k_swin<<<4096, 256, 0, stream>>>(x, n1g, n1b, wbuf, qkv_b, rtbl, biasT,
                                   wbuf + 27648, proj_b, n2g, n2b,
                                   wbuf + 36864, fc1_b, wbuf + 73728, fc2_b, out);
}

// Round 2
// 436.451 us; speedup vs baseline: 1.0735x; 1.0735x over previous
//
#include <hip/hip_runtime.h>
#include <hip/hip_fp16.h>
#include <math.h>

typedef _Float16 half_t;
typedef _Float16 half8 __attribute__((ext_vector_type(8)));
typedef float f32x4 __attribute__((ext_vector_type(4)));

#define MFMA(a, b, c) __builtin_amdgcn_mfma_f32_16x16x32_f16((a), (b), (c), 0, 0, 0)

static constexpr float kScale = 0.2041241452319315f;  // 24^-0.5
static constexpr int RS   = 104;  // hn / xn / rbuf row stride (halves)
static constexpr int QSTR = 200;  // qbuf row stride (Q|K -> O)
static constexpr int VTS  = 72;   // vT row stride (pbuf aliases per-head slice)
static constexpr int H1S  = 392;  // h1 half row stride

// ---- weights -> fp16, plus rel-pos bias expanded to [head][i][j] fp32 (64 KB)
__global__ __launch_bounds__(256) void k_convert(const float* __restrict__ qkv_w,
                                                 const float* __restrict__ proj_w,
                                                 const float* __restrict__ fc1_w,
                                                 const float* __restrict__ fc2_w,
                                                 const float* __restrict__ tbl,
                                                 half_t* __restrict__ wbuf,
                                                 float* __restrict__ biasT) {
  int i = blockIdx.x * 256 + threadIdx.x;  // grid 496*256 = 126976 >= 110592+16384
  if (i < 27648)        wbuf[i] = (half_t)qkv_w[i];
  else if (i < 36864)   wbuf[i] = (half_t)proj_w[i - 27648];
  else if (i < 73728)   wbuf[i] = (half_t)fc1_w[i - 36864];
  else if (i < 110592)  wbuf[i] = (half_t)fc2_w[i - 73728];
  else if (biasT != nullptr) {
    int j = i - 110592;                  // [head][i][j] : 4 * 64 * 64
    int h = j >> 12, rem = j & 4095;
    int ii = rem >> 6, jj = rem & 63;
    int ih = ii >> 3, iw = ii & 7, jh = jj >> 3, jw = jj & 7;
    biasT[j] = tbl[((ih - jh + 7) * 15 + (iw - jw + 7)) * 4 + h];
  }
}

// ===== whole Swin block fused, one 64-token window per 256-thread block =====
// Block-shared B for big GEMMs (each weight tile loaded ONCE per block);
// A-operands replicate through LDS. 52736 B LDS -> 3 blocks/CU.
//   S0 @0     25600: qbuf Q|K (P1-P2) -> O over Q cols -> h1h (32x392, MLP)
//   S1 @25600 13824: vT (P1-P2, pbuf per-head alias) -> rbuf (residual, f16)
//   S2 @39424 13312: hn (P0-P1) -> xn (D+)
__global__ __launch_bounds__(256, 3) void k_swin(
    const float* __restrict__ x,
    const float* __restrict__ n1g, const float* __restrict__ n1b,
    const half_t* __restrict__ qkvw, const float* __restrict__ qkv_b,
    const float* __restrict__ tbl_g, const float* __restrict__ biasT,
    const half_t* __restrict__ projw, const float* __restrict__ proj_b,
    const float* __restrict__ n2g, const float* __restrict__ n2b,
    const half_t* __restrict__ fc1w, const float* __restrict__ fc1b,
    const half_t* __restrict__ fc2w, const float* __restrict__ fc2b,
    float* __restrict__ out) {
  __shared__ __attribute__((aligned(16))) unsigned char smem[52736];
  half_t* qbuf = (half_t*)smem;
  half_t* h1h  = (half_t*)smem;
  half_t* vT   = (half_t*)(smem + 25600);
  half_t* rbuf = (half_t*)(smem + 25600);
  half_t* hn   = (half_t*)(smem + 39424);
  half_t* xn   = (half_t*)(smem + 39424);

  int tid = threadIdx.x;
  int wave = tid >> 6, lane = tid & 63;
  int l15 = lane & 15, quad = lane >> 4;
  int blk = blockIdx.x;                        // bb*64 + wh*8 + ww
  int bb = blk >> 6, wh = (blk >> 3) & 7, ww = blk & 7;

  // ---- P0: LN1, wave owns 16 rows; out -> hn (f16)
  {
    int tok = wave * 16 + l15;
    int sr = (wh * 8 + (tok >> 3) + 4) & 63;
    int sc = (ww * 8 + (tok & 7) + 4) & 63;
    const float* rp = x + ((size_t)bb * 4096 + sr * 64 + sc) * 96;
    float v[24];
    float s1 = 0.f, s2 = 0.f;
#pragma unroll
    for (int kt = 0; kt < 3; ++kt) {
      float4 a = *(const float4*)(rp + kt * 32 + quad * 8);
      float4 b = *(const float4*)(rp + kt * 32 + quad * 8 + 4);
      v[kt*8+0]=a.x; v[kt*8+1]=a.y; v[kt*8+2]=a.z; v[kt*8+3]=a.w;
      v[kt*8+4]=b.x; v[kt*8+5]=b.y; v[kt*8+6]=b.z; v[kt*8+7]=b.w;
    }
#pragma unroll
    for (int c = 0; c < 24; ++c) { s1 += v[c]; s2 += v[c] * v[c]; }
    s1 += __shfl_xor(s1, 16); s1 += __shfl_xor(s1, 32);
    s2 += __shfl_xor(s2, 16); s2 += __shfl_xor(s2, 32);
    float mu = s1 * (1.f / 96.f);
    float inv = rsqrtf(fmaxf(s2 * (1.f / 96.f) - mu * mu, 0.f) + 1e-5f);
#pragma unroll
    for (int kt = 0; kt < 3; ++kt) {
      int c0 = kt * 32 + quad * 8;
      float4 g0 = *(const float4*)(n1g + c0);
      float4 g1 = *(const float4*)(n1g + c0 + 4);
      float4 b0 = *(const float4*)(n1b + c0);
      float4 b1 = *(const float4*)(n1b + c0 + 4);
      float gg[8] = {g0.x,g0.y,g0.z,g0.w,g1.x,g1.y,g1.z,g1.w};
      float bv[8] = {b0.x,b0.y,b0.z,b0.w,b1.x,b1.y,b1.z,b1.w};
      half8 hh;
#pragma unroll
      for (int j = 0; j < 8; ++j)
        hh[j] = (half_t)((v[kt*8+j] - mu) * inv * gg[j] + bv[j]);
      *(half8*)(&hn[tok * RS + kt * 32 + quad * 8]) = hh;
    }
  }
  __syncthreads();  // B0

  // ---- P1: QKV GEMM, column-split (18 tiles round-robin; B loaded once/block)
  {
    half8 af[4][3];
#pragma unroll
    for (int g = 0; g < 4; ++g)
#pragma unroll
      for (int kt = 0; kt < 3; ++kt)
        af[g][kt] = *(const half8*)(&hn[(g * 16 + l15) * RS + kt * 32 + quad * 8]);
    for (int t = wave; t < 18; t += 4) {
      int n0 = t * 16 + l15;
      const half_t* wp = qkvw + (size_t)n0 * 96 + quad * 8;
      half8 b0 = *(const half8*)(wp);
      half8 b1 = *(const half8*)(wp + 32);
      half8 b2 = *(const half8*)(wp + 64);
      f32x4 acc[4] = {{0,0,0,0},{0,0,0,0},{0,0,0,0},{0,0,0,0}};
#pragma unroll
      for (int g = 0; g < 4; ++g) acc[g] = MFMA(af[g][0], b0, acc[g]);
#pragma unroll
      for (int g = 0; g < 4; ++g) acc[g] = MFMA(af[g][1], b1, acc[g]);
#pragma unroll
      for (int g = 0; g < 4; ++g) acc[g] = MFMA(af[g][2], b2, acc[g]);
      float bias = qkv_b[n0];
      if (t < 12) {                      // Q (scaled) and K -> qbuf col n0
        float sc_ = (t < 6) ? kScale : 1.f;
#pragma unroll
        for (int g = 0; g < 4; ++g)
#pragma unroll
          for (int r = 0; r < 4; ++r)
            qbuf[(g * 16 + quad * 4 + r) * QSTR + n0] = (half_t)((acc[g][r] + bias) * sc_);
      } else {                           // V -> vT [head][c][token]
        int vc = n0 - 192;
        int hd = vc / 24, c = vc - hd * 24;
#pragma unroll
        for (int g = 0; g < 4; ++g)
#pragma unroll
          for (int r = 0; r < 4; ++r)
            vT[hd * 24 * VTS + c * VTS + g * 16 + quad * 4 + r] = (half_t)(acc[g][r] + bias);
      }
    }
  }
  __syncthreads();  // B1: Q,K,V staged

  // ---- P2: attention, wave = head (all pieces wave-private after this point)
  {
    int head = wave;
    const half8 z8 = {};
    half8 kb[4], vb[2][2];
#pragma unroll
    for (int nt = 0; nt < 4; ++nt) {
      half8 t = *(const half8*)(&qbuf[(nt * 16 + l15) * QSTR + 96 + head * 24 + quad * 8]);
      kb[nt] = (quad < 3) ? t : z8;
    }
#pragma unroll
    for (int nt = 0; nt < 2; ++nt)
#pragma unroll
      for (int kt = 0; kt < 2; ++kt)
        vb[nt][kt] = *(const half8*)(&vT[head * 24 * VTS + (nt * 16 + l15) * VTS + kt * 32 + quad * 8]);

    int rj[4], jh_[4], jw_[4];
#pragma unroll
    for (int nt = 0; nt < 4; ++nt) {
      int j = nt * 16 + l15;
      jh_[nt] = j >> 3; jw_[nt] = j & 7;
      int rr = wh * 8 + jh_[nt], cc = ww * 8 + jw_[nt];
      rj[nt] = ((rr < 56) ? 0 : ((rr < 60) ? 1 : 2)) * 3 + ((cc < 56) ? 0 : ((cc < 60) ? 1 : 2));
    }

    half_t* pb = vT + head * 24 * VTS;   // wave-private alias over own vT slice
    f32x4 oacc[4][2];

#pragma unroll
    for (int g2 = 0; g2 < 4; ++g2) {
      half8 qt = *(const half8*)(&qbuf[(g2 * 16 + l15) * QSTR + head * 24 + quad * 8]);
      half8 qa = (quad < 3) ? qt : z8;
      f32x4 sv[4];
#pragma unroll
      for (int nt = 0; nt < 4; ++nt) {
        f32x4 a = {0, 0, 0, 0};
        sv[nt] = MFMA(qa, kb[nt], a);
      }
      float pinv[4];
#pragma unroll
      for (int r = 0; r < 4; ++r) {
        int i = g2 * 16 + quad * 4 + r;
        int ih = i >> 3, iw = i & 7;
        int rr = wh * 8 + ih, cc = ww * 8 + iw;
        int ri = ((rr < 56) ? 0 : ((rr < 60) ? 1 : 2)) * 3 + ((cc < 56) ? 0 : ((cc < 60) ? 1 : 2));
        float bvv[4];
        if (biasT != nullptr) {
          const float* bp = biasT + (head << 12) + (i << 6) + l15;
#pragma unroll
          for (int nt = 0; nt < 4; ++nt) bvv[nt] = bp[nt * 16];
        } else {
#pragma unroll
          for (int nt = 0; nt < 4; ++nt)
            bvv[nt] = tbl_g[((ih - jh_[nt] + 7) * 15 + (iw - jw_[nt] + 7)) * 4 + head];
        }
#pragma unroll
        for (int nt = 0; nt < 4; ++nt) {
          float val = sv[nt][r] + bvv[nt];
          if (ri != rj[nt]) val -= 100.f;
          sv[nt][r] = val;
        }
        float mx = fmaxf(fmaxf(sv[0][r], sv[1][r]), fmaxf(sv[2][r], sv[3][r]));
        mx = fmaxf(mx, __shfl_xor(mx, 1));
        mx = fmaxf(mx, __shfl_xor(mx, 2));
        mx = fmaxf(mx, __shfl_xor(mx, 4));
        mx = fmaxf(mx, __shfl_xor(mx, 8));
        float sum = 0.f;
#pragma unroll
        for (int nt = 0; nt < 4; ++nt) {
          float e = __expf(sv[nt][r] - mx);
          sv[nt][r] = e;
          sum += e;
        }
        sum += __shfl_xor(sum, 1);
        sum += __shfl_xor(sum, 2);
        sum += __shfl_xor(sum, 4);
        sum += __shfl_xor(sum, 8);
        pinv[r] = __builtin_amdgcn_rcpf(sum);
      }
      // normalized P (C layout) -> pb, read back as A-frags (same wave, in-order DS)
#pragma unroll
      for (int nt = 0; nt < 4; ++nt)
#pragma unroll
        for (int r = 0; r < 4; ++r)
          pb[(quad * 4 + r) * VTS + nt * 16 + l15] = (half_t)(sv[nt][r] * pinv[r]);
      __builtin_amdgcn_sched_barrier(0);
      half8 pa0 = *(const half8*)(&pb[l15 * VTS + quad * 8]);
      half8 pa1 = *(const half8*)(&pb[l15 * VTS + 32 + quad * 8]);
#pragma unroll
      for (int nt = 0; nt < 2; ++nt) {
        f32x4 a = {0, 0, 0, 0};
        a = MFMA(pa0, vb[nt][0], a);
        a = MFMA(pa1, vb[nt][1], a);
        oacc[g2][nt] = a;
      }
    }
    // O -> qbuf over own head's Q columns (no pre-barrier: disjoint per head)
#pragma unroll
    for (int g2 = 0; g2 < 4; ++g2)
#pragma unroll
      for (int nt = 0; nt < 2; ++nt) {
        int c = nt * 16 + l15;
        if (c < 24)
#pragma unroll
          for (int r = 0; r < 4; ++r)
            qbuf[(g2 * 16 + quad * 4 + r) * QSTR + head * 24 + c] = (half_t)oacc[g2][nt][r];
      }
  }
  __syncthreads();  // B2: all heads' O columns visible

  // ---- D: proj (row-split; B tiny) + residual + LN2 fused -> rbuf (S1) + xn (S2)
  {
    half8 oa[3];
#pragma unroll
    for (int kt = 0; kt < 3; ++kt)
      oa[kt] = *(const half8*)(&qbuf[(wave * 16 + l15) * QSTR + kt * 32 + quad * 8]);
    f32x4 acc[6];
#pragma unroll
    for (int t = 0; t < 6; ++t) {
      int n0 = t * 16 + l15;
      const half_t* wp = projw + (size_t)n0 * 96 + quad * 8;
      half8 b0 = *(const half8*)(wp);
      half8 b1 = *(const half8*)(wp + 32);
      half8 b2 = *(const half8*)(wp + 64);
      f32x4 a = {0, 0, 0, 0};
      a = MFMA(oa[0], b0, a);
      a = MFMA(oa[1], b1, a);
      a = MFMA(oa[2], b2, a);
      acc[t] = a;
    }
    float xv[6][4];
#pragma unroll
    for (int r = 0; r < 4; ++r) {
      int tok = wave * 16 + quad * 4 + r;
      int sr = (wh * 8 + (tok >> 3) + 4) & 63;
      int sc = (ww * 8 + (tok & 7) + 4) & 63;
      const float* xp = x + ((size_t)bb * 4096 + sr * 64 + sc) * 96 + l15;
#pragma unroll
      for (int t = 0; t < 6; ++t) xv[t][r] = xp[t * 16];
    }
    float rv[6][4];
    float s1[4] = {0, 0, 0, 0}, s2[4] = {0, 0, 0, 0};
#pragma unroll
    for (int t = 0; t < 6; ++t) {
      float pbv = proj_b[t * 16 + l15];
#pragma unroll
      for (int r = 0; r < 4; ++r) {
        float vvv = xv[t][r] + acc[t][r] + pbv;
        rv[t][r] = vvv;
        s1[r] += vvv; s2[r] += vvv * vvv;
      }
    }
    float mu[4], nv[4];
#pragma unroll
    for (int r = 0; r < 4; ++r) {
      s1[r] += __shfl_xor(s1[r], 1); s1[r] += __shfl_xor(s1[r], 2);
      s1[r] += __shfl_xor(s1[r], 4); s1[r] += __shfl_xor(s1[r], 8);
      s2[r] += __shfl_xor(s2[r], 1); s2[r] += __shfl_xor(s2[r], 2);
      s2[r] += __shfl_xor(s2[r], 4); s2[r] += __shfl_xor(s2[r], 8);
      mu[r] = s1[r] * (1.f / 96.f);
      nv[r] = rsqrtf(fmaxf(s2[r] * (1.f / 96.f) - mu[r] * mu[r], 0.f) + 1e-5f);
    }
#pragma unroll
    for (int t = 0; t < 6; ++t) {
      int n0 = t * 16 + l15;
      float gv = n2g[n0], bv = n2b[n0];
#pragma unroll
      for (int r = 0; r < 4; ++r) {
        int row = wave * 16 + quad * 4 + r;
        rbuf[row * RS + n0] = (half_t)rv[t][r];
        xn[row * RS + n0] = (half_t)((rv[t][r] - mu[r]) * nv[r] * gv + bv);
      }
    }
  }
  __syncthreads();  // B3: xn + rbuf ready

  // ---- P5/P6: MLP in two 32-row halves; column-split (B once/block); h1h over qbuf
  for (int hb = 0; hb < 2; ++hb) {
    {  // P5: fc1 + GELU (sigmoid form)
      half8 a5[2][3];
#pragma unroll
      for (int g2 = 0; g2 < 2; ++g2)
#pragma unroll
        for (int kt = 0; kt < 3; ++kt)
          a5[g2][kt] = *(const half8*)(&xn[((hb * 2 + g2) * 16 + l15) * RS + kt * 32 + quad * 8]);
      for (int t = wave; t < 24; t += 4) {
        int n0 = t * 16 + l15;
        const half_t* wp = fc1w + (size_t)n0 * 96 + quad * 8;
        half8 b0 = *(const half8*)(wp);
        half8 b1 = *(const half8*)(wp + 32);
        half8 b2 = *(const half8*)(wp + 64);
        f32x4 acc[2] = {{0,0,0,0},{0,0,0,0}};
#pragma unroll
        for (int g2 = 0; g2 < 2; ++g2) acc[g2] = MFMA(a5[g2][0], b0, acc[g2]);
#pragma unroll
        for (int g2 = 0; g2 < 2; ++g2) acc[g2] = MFMA(a5[g2][1], b1, acc[g2]);
#pragma unroll
        for (int g2 = 0; g2 < 2; ++g2) acc[g2] = MFMA(a5[g2][2], b2, acc[g2]);
        float bias = fc1b[n0];
#pragma unroll
        for (int g2 = 0; g2 < 2; ++g2)
#pragma unroll
          for (int r = 0; r < 4; ++r) {
            float vvv = acc[g2][r] + bias;
            // GELU: v * sigmoid(v*(1.5957691 + 0.14270963*v^2))
            float u = vvv * (1.5957691216f + 0.1427096322f * vvv * vvv);
            float g = vvv * __builtin_amdgcn_rcpf(1.f + __expf(-u));
            h1h[(g2 * 16 + quad * 4 + r) * H1S + n0] = (half_t)g;
          }
      }
    }
    __syncthreads();
    {  // P6: fc2 + residual -> out (wave-pair split)
      int rt = wave >> 1, chh = wave & 1;
      half8 a2[12];
#pragma unroll
      for (int kt = 0; kt < 12; ++kt)
        a2[kt] = *(const half8*)(&h1h[(rt * 16 + l15) * H1S + kt * 32 + quad * 8]);
#pragma unroll
      for (int i = 0; i < 3; ++i) {
        int t = chh * 3 + i;
        f32x4 acc = {0, 0, 0, 0};
#pragma unroll
        for (int kt = 0; kt < 12; ++kt) {
          half8 bf = *(const half8*)(fc2w + (size_t)(t * 16 + l15) * 384 + kt * 32 + quad * 8);
          acc = MFMA(a2[kt], bf, acc);
        }
        int col = t * 16 + l15;
        float bias = fc2b[col];
#pragma unroll
        for (int r = 0; r < 4; ++r) {
          int tok = hb * 32 + rt * 16 + quad * 4 + r;
          int sr = (wh * 8 + (tok >> 3) + 4) & 63;
          int sc = (ww * 8 + (tok & 7) + 4) & 63;
          size_t fidx = ((size_t)bb * 4096 + sr * 64 + sc) * 96 + col;
          out[fidx] = (float)rbuf[tok * RS + col] + acc[r] + bias;
        }
      }
    }
    __syncthreads();
  }
}

extern "C" void kernel_launch(void* const* d_in, const int* in_sizes, int n_in,
                              void* d_out, int out_size, void* d_ws, size_t ws_size,
                              hipStream_t stream) {
  const float* x      = (const float*)d_in[0];
  const float* n1g    = (const float*)d_in[1];
  const float* n1b    = (const float*)d_in[2];
  const float* qkv_w  = (const float*)d_in[3];
  const float* qkv_b  = (const float*)d_in[4];
  const float* rtbl   = (const float*)d_in[5];
  const float* proj_w = (const float*)d_in[6];
  const float* proj_b = (const float*)d_in[7];
  const float* n2g    = (const float*)d_in[8];
  const float* n2b    = (const float*)d_in[9];
  const float* fc1_w  = (const float*)d_in[10];
  const float* fc1_b  = (const float*)d_in[11];
  const float* fc2_w  = (const float*)d_in[12];
  const float* fc2_b  = (const float*)d_in[13];
  float* out = (float*)d_out;

  if (ws_size < 221184) return;
  half_t* wbuf = (half_t*)d_ws;
  float* biasT = (ws_size >= 221184 + 65536) ? (float*)((char*)d_ws + 221184) : nullptr;

  k_convert<<<496, 256, 0, stream>>>(qkv_w, proj_w, fc1_w, fc2_w, rtbl, wbuf, biasT);
  k_swin<<<4096, 256, 0, stream>>>(x, n1g, n1b, wbuf, qkv_b, rtbl, biasT,
                                   wbuf + 27648, proj_b, n2g, n2b,
                                   wbuf + 36864, fc1_b, wbuf + 73728, fc2_b, out);
}

// Round 3
// 406.799 us; speedup vs baseline: 1.1518x; 1.0729x over previous
//
#include <hip/hip_runtime.h>
#include <hip/hip_fp16.h>
#include <math.h>

typedef _Float16 half_t;
typedef _Float16 half8 __attribute__((ext_vector_type(8)));
typedef float f32x4 __attribute__((ext_vector_type(4)));

#define MFMA(a, b, c) __builtin_amdgcn_mfma_f32_16x16x32_f16((a), (b), (c), 0, 0, 0)
// LDS-only barrier: waits lgkmcnt (LDS) but leaves global (vmcnt) prefetch loads
// in flight. Legal here because ALL cross-wave data flows through LDS and 'out'
// is never re-read. "memory" clobber pins LDS stores before / reads after.
#define BARRIER() asm volatile("s_waitcnt lgkmcnt(0)\n\ts_barrier" ::: "memory")

static constexpr float kScale = 0.2041241452319315f;  // 24^-0.5
static constexpr int RS   = 104;  // hn / xn / rbuf row stride (halves)
static constexpr int QSTR = 200;  // qbuf row stride (Q|K -> O)
static constexpr int VTS  = 72;   // vT row stride (pbuf aliases per-head slice)
static constexpr int H1S  = 392;  // h1 half row stride

struct W3 { half8 b0, b1, b2; float bias; };

__device__ __forceinline__ W3 ld_w3(const half_t* w, const float* bv, int n0, int qo) {
  W3 r;
  const half_t* wp = w + (size_t)n0 * 96 + qo;
  r.b0 = *(const half8*)(wp);
  r.b1 = *(const half8*)(wp + 32);
  r.b2 = *(const half8*)(wp + 64);
  r.bias = bv[n0];
  return r;
}

__device__ __forceinline__ void qkv_tile(const W3& w, int t, int l15, int quad,
                                         const half8 (&af)[4][3],
                                         half_t* qbuf, half_t* vT) {
  f32x4 acc[4] = {{0,0,0,0},{0,0,0,0},{0,0,0,0},{0,0,0,0}};
#pragma unroll
  for (int g = 0; g < 4; ++g) acc[g] = MFMA(af[g][0], w.b0, acc[g]);
#pragma unroll
  for (int g = 0; g < 4; ++g) acc[g] = MFMA(af[g][1], w.b1, acc[g]);
#pragma unroll
  for (int g = 0; g < 4; ++g) acc[g] = MFMA(af[g][2], w.b2, acc[g]);
  int n0 = t * 16 + l15;
  if (t < 12) {                      // Q (scaled) and K -> qbuf col n0
    float sc_ = (t < 6) ? kScale : 1.f;
#pragma unroll
    for (int g = 0; g < 4; ++g)
#pragma unroll
      for (int r = 0; r < 4; ++r)
        qbuf[(g * 16 + quad * 4 + r) * QSTR + n0] = (half_t)((acc[g][r] + w.bias) * sc_);
  } else {                           // V -> vT [head][c][token]
    int vc = n0 - 192;
    int hd = vc / 24, c = vc - hd * 24;
#pragma unroll
    for (int g = 0; g < 4; ++g)
#pragma unroll
      for (int r = 0; r < 4; ++r)
        vT[hd * 24 * VTS + c * VTS + g * 16 + quad * 4 + r] = (half_t)(acc[g][r] + w.bias);
  }
}

__device__ __forceinline__ void fc1_tile(const W3& w, int t, int l15, int quad,
                                         const half8 (&a5)[2][3], half_t* h1h) {
  f32x4 a0 = {0,0,0,0}, a1 = {0,0,0,0};
  a0 = MFMA(a5[0][0], w.b0, a0); a1 = MFMA(a5[1][0], w.b0, a1);
  a0 = MFMA(a5[0][1], w.b1, a0); a1 = MFMA(a5[1][1], w.b1, a1);
  a0 = MFMA(a5[0][2], w.b2, a0); a1 = MFMA(a5[1][2], w.b2, a1);
  int n0 = t * 16 + l15;
#pragma unroll
  for (int g2 = 0; g2 < 2; ++g2) {
    const f32x4& ac = g2 ? a1 : a0;
#pragma unroll
    for (int r = 0; r < 4; ++r) {
      float vvv = ac[r] + w.bias;
      // GELU: v * sigmoid(v*(1.5957691 + 0.14270963*v^2))
      float u = vvv * (1.5957691216f + 0.1427096322f * vvv * vvv);
      float g = vvv * __builtin_amdgcn_rcpf(1.f + __expf(-u));
      h1h[(g2 * 16 + quad * 4 + r) * H1S + n0] = (half_t)g;
    }
  }
}

__device__ __forceinline__ void fc2_ld(const half_t* fc2w, int t, int l15, int qo,
                                       half8 (&bf)[12]) {
#pragma unroll
  for (int kt = 0; kt < 12; ++kt)
    bf[kt] = *(const half8*)(fc2w + (size_t)(t * 16 + l15) * 384 + kt * 32 + qo);
}

__device__ __forceinline__ void fc2_tile(const half8 (&a2)[12], const half8 (&bf)[12],
                                         int t, int hb, int rt, int l15, int quad,
                                         int wh, int ww, int bb,
                                         const float* fc2b, const half_t* rbuf,
                                         float* out) {
  f32x4 acc = {0,0,0,0};
#pragma unroll
  for (int kt = 0; kt < 12; ++kt) acc = MFMA(a2[kt], bf[kt], acc);
  int col = t * 16 + l15;
  float bias = fc2b[col];
#pragma unroll
  for (int r = 0; r < 4; ++r) {
    int tok = hb * 32 + rt * 16 + quad * 4 + r;
    int sr = (wh * 8 + (tok >> 3) + 4) & 63;
    int sc = (ww * 8 + (tok & 7) + 4) & 63;
    out[((size_t)bb * 4096 + sr * 64 + sc) * 96 + col] = (float)rbuf[tok * RS + col] + acc[r] + bias;
  }
}

__device__ __forceinline__ void p5_pass(int hb, int wave, int l15, int quad, int qo, int chh,
                                        const half_t* xn, half_t* h1h,
                                        const half_t* fc1w, const float* fc1b,
                                        const half_t* fc2w,
                                        W3& f1A, W3& f1B, half8 (&bfA)[12]) {
  half8 a5[2][3];
#pragma unroll
  for (int g2 = 0; g2 < 2; ++g2)
#pragma unroll
    for (int kt = 0; kt < 3; ++kt)
      a5[g2][kt] = *(const half8*)(&xn[((hb * 2 + g2) * 16 + l15) * RS + kt * 32 + quad * 8]);
  W3 f1C = ld_w3(fc1w, fc1b, (wave + 8) * 16 + l15, qo);
  fc1_tile(f1A, wave, l15, quad, a5, h1h);
  f1A = ld_w3(fc1w, fc1b, (wave + 12) * 16 + l15, qo);
  fc1_tile(f1B, wave + 4, l15, quad, a5, h1h);
  f1B = ld_w3(fc1w, fc1b, (wave + 16) * 16 + l15, qo);
  fc1_tile(f1C, wave + 8, l15, quad, a5, h1h);
  f1C = ld_w3(fc1w, fc1b, (wave + 20) * 16 + l15, qo);
  fc1_tile(f1A, wave + 12, l15, quad, a5, h1h);
  fc2_ld(fc2w, chh * 3 + 0, l15, qo, bfA);   // prefetch fc2 tile 0 for P6
  fc1_tile(f1B, wave + 16, l15, quad, a5, h1h);
  fc1_tile(f1C, wave + 20, l15, quad, a5, h1h);
}

__device__ __forceinline__ void p6_pass(int hb, int wave, int l15, int quad, int qo, int chh,
                                        int wh, int ww, int bb, bool pre_fc1,
                                        const half_t* h1h, const half_t* rbuf,
                                        const half_t* fc2w, const float* fc2b,
                                        const half_t* fc1w, const float* fc1b,
                                        float* out,
                                        W3& f1A, W3& f1B, half8 (&bfA)[12], half8 (&bfB)[12]) {
  int rt = wave >> 1;
  half8 a2[12];
#pragma unroll
  for (int kt = 0; kt < 12; ++kt)
    a2[kt] = *(const half8*)(&h1h[(rt * 16 + l15) * H1S + kt * 32 + quad * 8]);
  fc2_ld(fc2w, chh * 3 + 1, l15, qo, bfB);
  fc2_tile(a2, bfA, chh * 3 + 0, hb, rt, l15, quad, wh, ww, bb, fc2b, rbuf, out);
  fc2_ld(fc2w, chh * 3 + 2, l15, qo, bfA);
  fc2_tile(a2, bfB, chh * 3 + 1, hb, rt, l15, quad, wh, ww, bb, fc2b, rbuf, out);
  if (pre_fc1) {                     // re-issue fc1 tiles for the hb=1 P5 pass
    f1A = ld_w3(fc1w, fc1b, wave * 16 + l15, qo);
    f1B = ld_w3(fc1w, fc1b, (wave + 4) * 16 + l15, qo);
  }
  fc2_tile(a2, bfA, chh * 3 + 2, hb, rt, l15, quad, wh, ww, bb, fc2b, rbuf, out);
}

// ---- weights -> fp16, plus rel-pos bias expanded to [head][i][j] fp32 (64 KB)
__global__ __launch_bounds__(256) void k_convert(const float* __restrict__ qkv_w,
                                                 const float* __restrict__ proj_w,
                                                 const float* __restrict__ fc1_w,
                                                 const float* __restrict__ fc2_w,
                                                 const float* __restrict__ tbl,
                                                 half_t* __restrict__ wbuf,
                                                 float* __restrict__ biasT) {
  int i = blockIdx.x * 256 + threadIdx.x;
  if (i < 27648)        wbuf[i] = (half_t)qkv_w[i];
  else if (i < 36864)   wbuf[i] = (half_t)proj_w[i - 27648];
  else if (i < 73728)   wbuf[i] = (half_t)fc1_w[i - 36864];
  else if (i < 110592)  wbuf[i] = (half_t)fc2_w[i - 73728];
  else if (biasT != nullptr) {
    int j = i - 110592;                  // [head][i][j] : 4 * 64 * 64
    int h = j >> 12, rem = j & 4095;
    int ii = rem >> 6, jj = rem & 63;
    int ih = ii >> 3, iw = ii & 7, jh = jj >> 3, jw = jj & 7;
    biasT[j] = tbl[((ih - jh + 7) * 15 + (iw - jw + 7)) * 4 + h];
  }
}

// ===== whole Swin block fused; block-shared B tiles, LDS-only barriers,
// deep cross-phase register prefetch of all weights. 52736 B LDS, 3 blocks/CU.
__global__ __launch_bounds__(256, 3) void k_swin(
    const float* __restrict__ x,
    const float* __restrict__ n1g, const float* __restrict__ n1b,
    const half_t* __restrict__ qkvw, const float* __restrict__ qkv_b,
    const float* __restrict__ tbl_g, const float* __restrict__ biasT,
    const half_t* __restrict__ projw, const float* __restrict__ proj_b,
    const float* __restrict__ n2g, const float* __restrict__ n2b,
    const half_t* __restrict__ fc1w, const float* __restrict__ fc1b,
    const half_t* __restrict__ fc2w, const float* __restrict__ fc2b,
    float* __restrict__ out) {
  __shared__ __attribute__((aligned(16))) unsigned char smem[52736];
  half_t* qbuf = (half_t*)smem;
  half_t* h1h  = (half_t*)smem;
  half_t* vT   = (half_t*)(smem + 25600);
  half_t* rbuf = (half_t*)(smem + 25600);
  half_t* hn   = (half_t*)(smem + 39424);
  half_t* xn   = (half_t*)(smem + 39424);

  int tid = threadIdx.x;
  int wave = tid >> 6, lane = tid & 63;
  int l15 = lane & 15, quad = lane >> 4;
  int qo = quad * 8, chh = wave & 1;
  int blk = blockIdx.x;                        // bb*64 + wh*8 + ww
  int bb = blk >> 6, wh = (blk >> 3) & 7, ww = blk & 7;

  // ---- P0: LN1 (x loads issued first; first two QKV weight tiles prefetched)
  float v[24];
  {
    int tok = wave * 16 + l15;
    int sr = (wh * 8 + (tok >> 3) + 4) & 63;
    int sc = (ww * 8 + (tok & 7) + 4) & 63;
    const float* rp = x + ((size_t)bb * 4096 + sr * 64 + sc) * 96;
#pragma unroll
    for (int kt = 0; kt < 3; ++kt) {
      float4 a = *(const float4*)(rp + kt * 32 + qo);
      float4 b = *(const float4*)(rp + kt * 32 + qo + 4);
      v[kt*8+0]=a.x; v[kt*8+1]=a.y; v[kt*8+2]=a.z; v[kt*8+3]=a.w;
      v[kt*8+4]=b.x; v[kt*8+5]=b.y; v[kt*8+6]=b.z; v[kt*8+7]=b.w;
    }
  }
  W3 qA = ld_w3(qkvw, qkv_b, wave * 16 + l15, qo);
  W3 qB = ld_w3(qkvw, qkv_b, (wave + 4) * 16 + l15, qo);
  {
    int tok = wave * 16 + l15;
    float s1 = 0.f, s2 = 0.f;
#pragma unroll
    for (int c = 0; c < 24; ++c) { s1 += v[c]; s2 += v[c] * v[c]; }
    s1 += __shfl_xor(s1, 16); s1 += __shfl_xor(s1, 32);
    s2 += __shfl_xor(s2, 16); s2 += __shfl_xor(s2, 32);
    float mu = s1 * (1.f / 96.f);
    float inv = rsqrtf(fmaxf(s2 * (1.f / 96.f) - mu * mu, 0.f) + 1e-5f);
#pragma unroll
    for (int kt = 0; kt < 3; ++kt) {
      int c0 = kt * 32 + qo;
      float4 g0 = *(const float4*)(n1g + c0);
      float4 g1 = *(const float4*)(n1g + c0 + 4);
      float4 b0 = *(const float4*)(n1b + c0);
      float4 b1 = *(const float4*)(n1b + c0 + 4);
      float gg[8] = {g0.x,g0.y,g0.z,g0.w,g1.x,g1.y,g1.z,g1.w};
      float bv[8] = {b0.x,b0.y,b0.z,b0.w,b1.x,b1.y,b1.z,b1.w};
      half8 hh;
#pragma unroll
      for (int j = 0; j < 8; ++j)
        hh[j] = (half_t)((v[kt*8+j] - mu) * inv * gg[j] + bv[j]);
      *(half8*)(&hn[tok * RS + kt * 32 + qo]) = hh;
    }
  }
  BARRIER();  // B0

  // ---- P1: QKV GEMM, column-split, 2-deep weight pipeline
  {
    W3 qC = ld_w3(qkvw, qkv_b, (wave + 8) * 16 + l15, qo);
    half8 af[4][3];
#pragma unroll
    for (int g = 0; g < 4; ++g)
#pragma unroll
      for (int kt = 0; kt < 3; ++kt)
        af[g][kt] = *(const half8*)(&hn[(g * 16 + l15) * RS + kt * 32 + qo]);
    qkv_tile(qA, wave, l15, quad, af, qbuf, vT);
    qA = ld_w3(qkvw, qkv_b, (wave + 12) * 16 + l15, qo);
    qkv_tile(qB, wave + 4, l15, quad, af, qbuf, vT);
    if (wave < 2) qB = ld_w3(qkvw, qkv_b, (wave + 16) * 16 + l15, qo);
    qkv_tile(qC, wave + 8, l15, quad, af, qbuf, vT);
    qkv_tile(qA, wave + 12, l15, quad, af, qbuf, vT);
    if (wave < 2) qkv_tile(qB, wave + 16, l15, quad, af, qbuf, vT);
  }
  // prefetch this head's rel-pos bias (64 floats) across B1
  int head = wave;
  float bt[4][16];
  if (biasT != nullptr) {
#pragma unroll
    for (int g2 = 0; g2 < 4; ++g2)
#pragma unroll
      for (int r = 0; r < 4; ++r) {
        const float* bp = biasT + (head << 12) + ((g2 * 16 + quad * 4 + r) << 6) + l15;
#pragma unroll
        for (int nt = 0; nt < 4; ++nt) bt[g2][r * 4 + nt] = bp[nt * 16];
      }
  }
  BARRIER();  // B1: Q,K,V staged

  // ---- P2: attention, wave = head
  {
    const half8 z8 = {};
    half8 kb[4], vb[2][2];
#pragma unroll
    for (int nt = 0; nt < 4; ++nt) {
      half8 t = *(const half8*)(&qbuf[(nt * 16 + l15) * QSTR + 96 + head * 24 + qo]);
      kb[nt] = (quad < 3) ? t : z8;
    }
#pragma unroll
    for (int nt = 0; nt < 2; ++nt)
#pragma unroll
      for (int kt = 0; kt < 2; ++kt)
        vb[nt][kt] = *(const half8*)(&vT[head * 24 * VTS + (nt * 16 + l15) * VTS + kt * 32 + qo]);

    int rj[4], jh_[4], jw_[4];
#pragma unroll
    for (int nt = 0; nt < 4; ++nt) {
      int j = nt * 16 + l15;
      jh_[nt] = j >> 3; jw_[nt] = j & 7;
      int rr = wh * 8 + jh_[nt], cc = ww * 8 + jw_[nt];
      rj[nt] = ((rr < 56) ? 0 : ((rr < 60) ? 1 : 2)) * 3 + ((cc < 56) ? 0 : ((cc < 60) ? 1 : 2));
    }

    half_t* pb = vT + head * 24 * VTS;   // wave-private alias over own vT slice
    f32x4 oacc[4][2];

#pragma unroll
    for (int g2 = 0; g2 < 4; ++g2) {
      half8 qt = *(const half8*)(&qbuf[(g2 * 16 + l15) * QSTR + head * 24 + qo]);
      half8 qa = (quad < 3) ? qt : z8;
      f32x4 sv[4];
#pragma unroll
      for (int nt = 0; nt < 4; ++nt) {
        f32x4 a = {0, 0, 0, 0};
        sv[nt] = MFMA(qa, kb[nt], a);
      }
      float pinv[4];
#pragma unroll
      for (int r = 0; r < 4; ++r) {
        int i = g2 * 16 + quad * 4 + r;
        int ih = i >> 3, iw = i & 7;
        int rr = wh * 8 + ih, cc = ww * 8 + iw;
        int ri = ((rr < 56) ? 0 : ((rr < 60) ? 1 : 2)) * 3 + ((cc < 56) ? 0 : ((cc < 60) ? 1 : 2));
#pragma unroll
        for (int nt = 0; nt < 4; ++nt) {
          float bvv;
          if (biasT != nullptr) bvv = bt[g2][r * 4 + nt];
          else bvv = tbl_g[((ih - jh_[nt] + 7) * 15 + (iw - jw_[nt] + 7)) * 4 + head];
          float val = sv[nt][r] + bvv;
          if (ri != rj[nt]) val -= 100.f;
          sv[nt][r] = val;
        }
        float mx = fmaxf(fmaxf(sv[0][r], sv[1][r]), fmaxf(sv[2][r], sv[3][r]));
        mx = fmaxf(mx, __shfl_xor(mx, 1));
        mx = fmaxf(mx, __shfl_xor(mx, 2));
        mx = fmaxf(mx, __shfl_xor(mx, 4));
        mx = fmaxf(mx, __shfl_xor(mx, 8));
        float sum = 0.f;
#pragma unroll
        for (int nt = 0; nt < 4; ++nt) {
          float e = __expf(sv[nt][r] - mx);
          sv[nt][r] = e;
          sum += e;
        }
        sum += __shfl_xor(sum, 1);
        sum += __shfl_xor(sum, 2);
        sum += __shfl_xor(sum, 4);
        sum += __shfl_xor(sum, 8);
        pinv[r] = __builtin_amdgcn_rcpf(sum);
      }
#pragma unroll
      for (int nt = 0; nt < 4; ++nt)
#pragma unroll
        for (int r = 0; r < 4; ++r)
          pb[(quad * 4 + r) * VTS + nt * 16 + l15] = (half_t)(sv[nt][r] * pinv[r]);
      __builtin_amdgcn_sched_barrier(0);
      half8 pa0 = *(const half8*)(&pb[l15 * VTS + qo]);
      half8 pa1 = *(const half8*)(&pb[l15 * VTS + 32 + qo]);
#pragma unroll
      for (int nt = 0; nt < 2; ++nt) {
        f32x4 a = {0, 0, 0, 0};
        a = MFMA(pa0, vb[nt][0], a);
        a = MFMA(pa1, vb[nt][1], a);
        oacc[g2][nt] = a;
      }
    }
    // O -> qbuf over own head's Q columns (intra-wave in-order; no barrier needed)
#pragma unroll
    for (int g2 = 0; g2 < 4; ++g2)
#pragma unroll
      for (int nt = 0; nt < 2; ++nt) {
        int c = nt * 16 + l15;
        if (c < 24)
#pragma unroll
          for (int r = 0; r < 4; ++r)
            qbuf[(g2 * 16 + quad * 4 + r) * QSTR + head * 24 + c] = (half_t)oacc[g2][nt][r];
      }
  }
  // prefetch across B2: all 6 proj tiles, residual x, LN2 gamma/beta
  W3 pw[6];
#pragma unroll
  for (int t = 0; t < 6; ++t) pw[t] = ld_w3(projw, proj_b, t * 16 + l15, qo);
  float xv[6][4];
#pragma unroll
  for (int r = 0; r < 4; ++r) {
    int tok2 = wave * 16 + quad * 4 + r;
    int sr = (wh * 8 + (tok2 >> 3) + 4) & 63;
    int sc = (ww * 8 + (tok2 & 7) + 4) & 63;
    const float* xp = x + ((size_t)bb * 4096 + sr * 64 + sc) * 96 + l15;
#pragma unroll
    for (int t = 0; t < 6; ++t) xv[t][r] = xp[t * 16];
  }
  float gn2[6], bn2[6];
#pragma unroll
  for (int t = 0; t < 6; ++t) { gn2[t] = n2g[t * 16 + l15]; bn2[t] = n2b[t * 16 + l15]; }
  BARRIER();  // B2: all heads' O columns visible

  // ---- D: proj (row-split) + residual + LN2 fused -> rbuf + xn
  {
    half8 oa[3];
#pragma unroll
    for (int kt = 0; kt < 3; ++kt)
      oa[kt] = *(const half8*)(&qbuf[(wave * 16 + l15) * QSTR + kt * 32 + qo]);
    f32x4 acc[6];
#pragma unroll
    for (int t = 0; t < 6; ++t) {
      f32x4 a = {0, 0, 0, 0};
      a = MFMA(oa[0], pw[t].b0, a);
      a = MFMA(oa[1], pw[t].b1, a);
      a = MFMA(oa[2], pw[t].b2, a);
      acc[t] = a;
    }
    float rv[6][4];
    float s1[4] = {0, 0, 0, 0}, s2[4] = {0, 0, 0, 0};
#pragma unroll
    for (int t = 0; t < 6; ++t)
#pragma unroll
      for (int r = 0; r < 4; ++r) {
        float vvv = xv[t][r] + acc[t][r] + pw[t].bias;
        rv[t][r] = vvv;
        s1[r] += vvv; s2[r] += vvv * vvv;
      }
    float mu[4], nv[4];
#pragma unroll
    for (int r = 0; r < 4; ++r) {
      s1[r] += __shfl_xor(s1[r], 1); s1[r] += __shfl_xor(s1[r], 2);
      s1[r] += __shfl_xor(s1[r], 4); s1[r] += __shfl_xor(s1[r], 8);
      s2[r] += __shfl_xor(s2[r], 1); s2[r] += __shfl_xor(s2[r], 2);
      s2[r] += __shfl_xor(s2[r], 4); s2[r] += __shfl_xor(s2[r], 8);
      mu[r] = s1[r] * (1.f / 96.f);
      nv[r] = rsqrtf(fmaxf(s2[r] * (1.f / 96.f) - mu[r] * mu[r], 0.f) + 1e-5f);
    }
#pragma unroll
    for (int t = 0; t < 6; ++t) {
      int n0 = t * 16 + l15;
#pragma unroll
      for (int r = 0; r < 4; ++r) {
        int row = wave * 16 + quad * 4 + r;
        rbuf[row * RS + n0] = (half_t)rv[t][r];
        xn[row * RS + n0] = (half_t)((rv[t][r] - mu[r]) * nv[r] * gn2[t] + bn2[t]);
      }
    }
  }
  // prefetch first two fc1 tiles across B3
  W3 f1A = ld_w3(fc1w, fc1b, wave * 16 + l15, qo);
  W3 f1B = ld_w3(fc1w, fc1b, (wave + 4) * 16 + l15, qo);
  half8 bfA[12], bfB[12];
  BARRIER();  // B3: xn + rbuf ready

  // ---- MLP: two 32-row halves, fully software-pipelined
  p5_pass(0, wave, l15, quad, qo, chh, xn, h1h, fc1w, fc1b, fc2w, f1A, f1B, bfA);
  BARRIER();  // B4
  p6_pass(0, wave, l15, quad, qo, chh, wh, ww, bb, true,
          h1h, rbuf, fc2w, fc2b, fc1w, fc1b, out, f1A, f1B, bfA, bfB);
  BARRIER();  // B5
  p5_pass(1, wave, l15, quad, qo, chh, xn, h1h, fc1w, fc1b, fc2w, f1A, f1B, bfA);
  BARRIER();  // B6
  p6_pass(1, wave, l15, quad, qo, chh, wh, ww, bb, false,
          h1h, rbuf, fc2w, fc2b, fc1w, fc1b, out, f1A, f1B, bfA, bfB);
}

extern "C" void kernel_launch(void* const* d_in, const int* in_sizes, int n_in,
                              void* d_out, int out_size, void* d_ws, size_t ws_size,
                              hipStream_t stream) {
  const float* x      = (const float*)d_in[0];
  const float* n1g    = (const float*)d_in[1];
  const float* n1b    = (const float*)d_in[2];
  const float* qkv_w  = (const float*)d_in[3];
  const float* qkv_b  = (const float*)d_in[4];
  const float* rtbl   = (const float*)d_in[5];
  const float* proj_w = (const float*)d_in[6];
  const float* proj_b = (const float*)d_in[7];
  const float* n2g    = (const float*)d_in[8];
  const float* n2b    = (const float*)d_in[9];
  const float* fc1_w  = (const float*)d_in[10];
  const float* fc1_b  = (const float*)d_in[11];
  const float* fc2_w  = (const float*)d_in[12];
  const float* fc2_b  = (const float*)d_in[13];
  float* out = (float*)d_out;

  if (ws_size < 221184) return;
  half_t* wbuf = (half_t*)d_ws;
  float* biasT = (ws_size >= 221184 + 65536) ? (float*)((char*)d_ws + 221184) : nullptr;

  k_convert<<<496, 256, 0, stream>>>(qkv_w, proj_w, fc1_w, fc2_w, rtbl, wbuf, biasT);
  k_swin<<<4096, 256, 0, stream>>>(x, n1g, n1b, wbuf, qkv_b, rtbl, biasT,
                                   wbuf + 27648, proj_b, n2g, n2b,
                                   wbuf + 36864, fc1_b, wbuf + 73728, fc2_b, out);
}